// Round 7
// baseline (468.730 us; speedup 1.0000x reference)
//
#include <hip/hip_runtime.h>
#include <hip/hip_cooperative_groups.h>
#include <math.h>

namespace cg = cooperative_groups;

// WaveletKANClassifier, MI355X gfx950. fp32 I/O, bf16 MFMA compute.
//
// Round-10: (a) single cooperative dispatch — pack phase inside the kernel
// (165 blocks x 8 waves = 1320 tiles), grid.sync(), then 2x 64-row GEMM
// passes per block (grid 256 = exactly 1 block/CU, co-resident at <=256
// regs). Kills the pack dispatch + ~60us launch overhead (totals data:
// 2-dispatch overhead was 104-136us of 265).
// (b) store vectorization via in-reg 4x4 shfl butterfly transpose of the
// C/D fragments: 96 scalar stores/thread -> 24 float4 stores. Same bytes,
// 4x fewer VMEM instrs. Discriminates "per-CU VMEM instr-rate bound" vs
// "line-rate bound" (R3's occupancy-null proved a per-CU shared-resource
// pin; per-CU lines x ~5-7cyc == measured 320k cycles).

#define B_SZ  32768
#define DIN   768
#define DOUT  768
#define NWAV  48

// d_ws fragment-major layout (units: shorts). Fragment tile = 64 lanes x 8
// bf16 = 512 shorts; lane L holds M[c0+(L&31)][k0 + (L>>5)*8 + j].
#define WF_OFF   0        // W:  24 cb x 48 kb tiles = 589824
#define WPH_OFF  589824   // Wp hi: 2 ct x 48 kb = 49152
#define WPL_OFF  638976   // Wp lo: 49152
#define WCF_OFF  688128   // Wc: 24 cb x 3 kb = 36864

typedef short bf16x8 __attribute__((ext_vector_type(8)));
typedef float f32x16 __attribute__((ext_vector_type(16)));

__device__ __forceinline__ float bf2f(short u) {
    union { unsigned int i; float f; } v;
    v.i = ((unsigned int)(unsigned short)u) << 16;
    return v.f;
}
__device__ __forceinline__ short f2bf(float f) {
    union { float f; unsigned int i; } v; v.f = f;
    unsigned int r = v.i + 0x7FFFu + ((v.i >> 16) & 1u);  // RNE
    return (short)(r >> 16);
}

// ---------------------------------------------------------------- fused
// grid 256 x 512 thr. Phase 0: pack weights (blocks 0..164). grid.sync().
// Then 2 passes x (64 rows x 768 cols), 8 waves x [64r x 96c].
__global__ __launch_bounds__(512, 2) void fused_kernel(
    const float* __restrict__ x,  const float* __restrict__ W,
    const float* __restrict__ Wp, const float* __restrict__ Wc,
    short* __restrict__ ws,
    const float* __restrict__ bp, const float* __restrict__ sc,
    const float* __restrict__ tr,
    const float* __restrict__ bb, const float* __restrict__ bc,
    const float* __restrict__ gm, const float* __restrict__ bt,
    float* __restrict__ out)
{
    __shared__ __align__(16) short xh[2][64 * 72];
    __shared__ __align__(16) short xl[2][64 * 72];
    __shared__ float redS[64 * 8], redQ[64 * 8];
    __shared__ float muA[64], rsA[64];
    __shared__ unsigned flags[64];      // bit j: (row, haar j) boundary band
    __shared__ double dred[8];

    const int tid = threadIdx.x;
    const int L   = tid & 63;
    const int wv  = __builtin_amdgcn_readfirstlane(tid >> 6);  // wave-uniform
    const int lm  = L & 31, half = L >> 5;
    const int L8  = L * 8;
    const bool wi = (wv < 4);      // waves 0-3 also compute wi = x@Wp^T
    const int wv3 = wv * 3;
    const int wrt = wv & 1, wct = wv >> 1;     // wi tile for wv<4
    const int wct48 = wct * 48;

    // ---------------- phase 0: pack weights into ws (1320 fragment tiles)
    {
        const int gw = blockIdx.x * 8 + wv;
        if (gw < 1152) {                       // W [768 x 768]
            const int cb = gw / 48, kb = gw % 48;
            const int row = cb * 32 + lm;
            const int k = kb * 16 + half * 8;
            bf16x8 o;
#pragma unroll
            for (int j = 0; j < 8; j++) o[j] = f2bf(W[(size_t)row * DIN + k + j]);
            *reinterpret_cast<bf16x8*>(&ws[WF_OFF + (size_t)gw * 512 + L8]) = o;
        } else if (gw < 1248) {                // Wp [48 x 768], hi/lo, pad->64
            const int t = gw - 1152;
            const int ct = t / 48, kb = t % 48;
            const int j = ct * 32 + lm;
            const int k = kb * 16 + half * 8;
            bf16x8 h, l;
#pragma unroll
            for (int jj = 0; jj < 8; jj++) {
                float v = (j < NWAV) ? Wp[(size_t)j * DIN + k + jj] : 0.f;
                const short hh = f2bf(v);
                h[jj] = hh;
                l[jj] = f2bf(v - bf2f(hh));
            }
            *reinterpret_cast<bf16x8*>(&ws[WPH_OFF + (size_t)t * 512 + L8]) = h;
            *reinterpret_cast<bf16x8*>(&ws[WPL_OFF + (size_t)t * 512 + L8]) = l;
        } else if (gw < 1320) {                // Wc [768 x 48]
            const int t = gw - 1248;
            const int cb = t / 3, kb = t % 3;
            const int row = cb * 32 + lm;
            const int k = kb * 16 + half * 8;
            bf16x8 o;
#pragma unroll
            for (int jj = 0; jj < 8; jj++) o[jj] = f2bf(Wc[(size_t)row * NWAV + k + jj]);
            *reinterpret_cast<bf16x8*>(&ws[WCF_OFF + (size_t)t * 512 + L8]) = o;
        }
    }
    cg::this_grid().sync();

    const short* WF  = ws + WF_OFF;
    const short* WPH = ws + WPH_OFF;
    const short* WPL = ws + WPL_OFF;
    const short* WCF = ws + WCF_OFF;

    // staging role: thread -> (row, 8-k chunk); 8 threads per row
    const int srow = tid >> 3;
    const int sk   = (tid & 7) * 8;

    // transpose lane masks (4x4 butterfly within lane quads)
    const bool ib0 = (lm & 1) != 0, ib1 = (lm & 2) != 0;

#pragma unroll 1
    for (int pass = 0; pass < 2; ++pass) {
        const int r0 = (blockIdx.x + (pass << 8)) * 64;

        if (tid < 64) flags[tid] = 0u;

        f32x16 acc[2][3];          // [rt (row 32-block)][ct (col 32-block)]
#pragma unroll
        for (int rt = 0; rt < 2; rt++)
#pragma unroll
            for (int ct = 0; ct < 3; ct++)
#pragma unroll
                for (int g = 0; g < 16; g++) acc[rt][ct][g] = 0.f;
        f32x16 wacc;               // wi acc (waves 0-3)
#pragma unroll
        for (int g = 0; g < 16; g++) wacc[g] = 0.f;

        // ---- prologue: stage x chunk 0 into buf 0
        {
            const float4* xp = reinterpret_cast<const float4*>(&x[(size_t)(r0 + srow) * DIN + sk]);
            const float4 v0 = xp[0], v1 = xp[1];
            const float f[8] = {v0.x, v0.y, v0.z, v0.w, v1.x, v1.y, v1.z, v1.w};
            bf16x8 hh, ll;
#pragma unroll
            for (int i = 0; i < 8; i++) {
                const short h = f2bf(f[i]);
                hh[i] = h;
                ll[i] = f2bf(f[i] - bf2f(h));
            }
            *reinterpret_cast<bf16x8*>(&xh[0][srow * 72 + sk]) = hh;
            *reinterpret_cast<bf16x8*>(&xl[0][srow * 72 + sk]) = ll;
        }
        __syncthreads();

        // ---- K loop: 12 chunks of 64
        for (int k0i = 0; k0i < 12; ++k0i) {
            const int cur = k0i & 1;
            const int kb0 = k0i * 4;

            // (1) issue ALL B-fragment loads of this chunk, back-to-back
            bf16x8 bfr[4][3];
#pragma unroll
            for (int ks = 0; ks < 4; ++ks)
#pragma unroll
                for (int ct = 0; ct < 3; ++ct)
                    bfr[ks][ct] = *reinterpret_cast<const bf16x8*>(
                        &WF[((size_t)((wv3 + ct) * 48 + kb0 + ks)) * 512 + L8]);
            bf16x8 bwh[4], bwl[4];
            if (wi) {
#pragma unroll
                for (int ks = 0; ks < 4; ++ks) {
                    bwh[ks] = *reinterpret_cast<const bf16x8*>(
                        &WPH[((size_t)(wct48 + kb0 + ks)) * 512 + L8]);
                    bwl[ks] = *reinterpret_cast<const bf16x8*>(
                        &WPL[((size_t)(wct48 + kb0 + ks)) * 512 + L8]);
                }
            }

            // (2) x prefetch (consumed after the MFMA cluster)
            float4 v0, v1;
            if (k0i < 11) {
                const float4* xp = reinterpret_cast<const float4*>(
                    &x[(size_t)(r0 + srow) * DIN + (k0i + 1) * 64 + sk]);
                v0 = xp[0]; v1 = xp[1];
            }

            __builtin_amdgcn_sched_barrier(0);

            // (4) MFMA cluster
#pragma unroll
            for (int ks = 0; ks < 4; ++ks) {
                const bf16x8 a0 = *reinterpret_cast<bf16x8*>(
                    &xh[cur][lm * 72 + ks * 16 + half * 8]);
                const bf16x8 a1 = *reinterpret_cast<bf16x8*>(
                    &xh[cur][(32 + lm) * 72 + ks * 16 + half * 8]);
#pragma unroll
                for (int ct = 0; ct < 3; ++ct) {
                    acc[0][ct] = __builtin_amdgcn_mfma_f32_32x32x16_bf16(a0, bfr[ks][ct], acc[0][ct], 0, 0, 0);
                    acc[1][ct] = __builtin_amdgcn_mfma_f32_32x32x16_bf16(a1, bfr[ks][ct], acc[1][ct], 0, 0, 0);
                }
                if (wi) {
                    const bf16x8 ah = wrt ? a1 : a0;
                    const bf16x8 al = *reinterpret_cast<bf16x8*>(
                        &xl[cur][(wrt * 32 + lm) * 72 + ks * 16 + half * 8]);
                    wacc = __builtin_amdgcn_mfma_f32_32x32x16_bf16(ah, bwl[ks], wacc, 0, 0, 0);
                    wacc = __builtin_amdgcn_mfma_f32_32x32x16_bf16(al, bwh[ks], wacc, 0, 0, 0);
                    wacc = __builtin_amdgcn_mfma_f32_32x32x16_bf16(ah, bwh[ks], wacc, 0, 0, 0);
                }
            }

            // (5) stage next x chunk into 1-cur
            if (k0i < 11) {
                const float f[8] = {v0.x, v0.y, v0.z, v0.w, v1.x, v1.y, v1.z, v1.w};
                bf16x8 hh, ll;
#pragma unroll
                for (int i = 0; i < 8; i++) {
                    const short h = f2bf(f[i]);
                    hh[i] = h;
                    ll[i] = f2bf(f[i] - bf2f(h));
                }
                *reinterpret_cast<bf16x8*>(&xh[1 - cur][srow * 72 + sk]) = hh;
                *reinterpret_cast<bf16x8*>(&xl[1 - cur][srow * 72 + sk]) = ll;
            }
            __syncthreads();
        }

        // ---- wavelet activation + GELU -> wav tile in LDS (reuse xh[0])
        short* wavL = &xh[0][0];
        if (wi) {
            const int j = wct * 32 + lm;
            if (j < NWAV) {
                const float bpv = bp[j], scv = sc[j], trv = tr[j];
#pragma unroll
                for (int g = 0; g < 16; ++g) {
                    const int rowl = wrt * 32 + (g & 3) + 8 * (g >> 2) + 4 * half;  // C/D map
                    const float wiv = wacc[g] + bpv;
                    const float s = (wiv - trv) / scv;
                    float w;
                    if (j < 16) {
                        // haar: flag boundary band for the in-block recheck
                        const float dmin = fminf(fabsf(s), fminf(fabsf(s - 0.5f), fabsf(s - 1.0f)));
                        if (dmin < 2e-4f) atomicOr(&flags[rowl], 1u << j);
                        w = (s >= 0.f && s < 0.5f) ? 1.f : ((s >= 0.5f && s < 1.f) ? -1.f : 0.f);
                    } else if (j < 32) {
                        w = (1.f - s * s) * expf(-0.5f * s * s);
                    } else {
                        w = cosf(5.f * s) * expf(-0.5f * s * s);
                    }
                    const float gel = 0.5f * w * (1.f + erff(w * 0.70710678118654752f));
                    wavL[rowl * 72 + j] = f2bf(gel);
                }
            }
        }
        __syncthreads();

        // ---- block-parallel fp64 recheck of flagged (row, j) haar entries
#pragma unroll 1
        for (int fr = 0; fr < 64; ++fr) {
            unsigned m = flags[fr];
            while (m) {
                const int j = __ffs(m) - 1;
                m &= m - 1;
                const float* xr = &x[(size_t)(r0 + fr) * DIN];
                const float* wr = &Wp[(size_t)j * DIN];
                double a = (double)xr[tid] * (double)wr[tid];
                if (tid < DIN - 512)
                    a += (double)xr[tid + 512] * (double)wr[tid + 512];
                a += __shfl_xor(a, 1);  a += __shfl_xor(a, 2);
                a += __shfl_xor(a, 4);  a += __shfl_xor(a, 8);
                a += __shfl_xor(a, 16); a += __shfl_xor(a, 32);
                if (L == 0) dred[wv] = a;
                __syncthreads();
                if (tid == 0) {
                    double wid = (double)bp[j];
#pragma unroll
                    for (int i = 0; i < 8; i++) wid += dred[i];
                    const double sd = (wid - (double)tr[j]) / (double)sc[j];
                    const double w = (sd >= 0.0 && sd < 0.5) ? 1.0
                                   : ((sd >= 0.5 && sd < 1.0) ? -1.0 : 0.0);
                    const double gel = 0.5 * w * (1.0 + erf(w * 0.70710678118654752));
                    wavL[fr * 72 + j] = f2bf((float)gel);
                }
                __syncthreads();
            }
        }

        // ---- h += wav @ Wc^T  (K=48 -> 3 ksteps)
#pragma unroll
        for (int ks = 0; ks < 3; ++ks) {
            const bf16x8 a0 = *reinterpret_cast<bf16x8*>(&wavL[lm * 72 + ks * 16 + half * 8]);
            const bf16x8 a1 = *reinterpret_cast<bf16x8*>(&wavL[(32 + lm) * 72 + ks * 16 + half * 8]);
#pragma unroll
            for (int ct = 0; ct < 3; ++ct) {
                const bf16x8 b = *reinterpret_cast<const bf16x8*>(
                    &WCF[((size_t)((wv3 + ct) * 3 + ks)) * 512 + L8]);
                acc[0][ct] = __builtin_amdgcn_mfma_f32_32x32x16_bf16(a0, b, acc[0][ct], 0, 0, 0);
                acc[1][ct] = __builtin_amdgcn_mfma_f32_32x32x16_bf16(a1, b, acc[1][ct], 0, 0, 0);
            }
        }

        // ---- bias + LN reduction
        float bias[3];
#pragma unroll
        for (int ct = 0; ct < 3; ++ct) {
            const int col = wv * 96 + ct * 32 + lm;
            bias[ct] = bb[col] + bc[col];
        }
#pragma unroll
        for (int rt = 0; rt < 2; ++rt) {
#pragma unroll
            for (int g = 0; g < 16; ++g) {
                const float v0 = acc[rt][0][g] + bias[0];
                const float v1 = acc[rt][1][g] + bias[1];
                const float v2 = acc[rt][2][g] + bias[2];
                acc[rt][0][g] = v0; acc[rt][1][g] = v1; acc[rt][2][g] = v2;
                float s1 = v0 + v1 + v2;
                float s2 = v0 * v0 + v1 * v1 + v2 * v2;
                s1 += __shfl_xor(s1, 1);  s2 += __shfl_xor(s2, 1);
                s1 += __shfl_xor(s1, 2);  s2 += __shfl_xor(s2, 2);
                s1 += __shfl_xor(s1, 4);  s2 += __shfl_xor(s2, 4);
                s1 += __shfl_xor(s1, 8);  s2 += __shfl_xor(s2, 8);
                s1 += __shfl_xor(s1, 16); s2 += __shfl_xor(s2, 16);
                if (lm == 0) {
                    const int rowl = rt * 32 + (g & 3) + 8 * (g >> 2) + 4 * half;
                    redS[rowl * 8 + wv] = s1;
                    redQ[rowl * 8 + wv] = s2;
                }
            }
        }
        __syncthreads();
        if (tid < 64) {
            float S = 0.f, Q = 0.f;
#pragma unroll
            for (int i = 0; i < 8; i++) { S += redS[tid * 8 + i]; Q += redQ[tid * 8 + i]; }
            const float mu = S * (1.f / 768.f);
            const float var = Q * (1.f / 768.f) - mu * mu;
            muA[tid] = mu;
            rsA[tid] = rsqrtf(var + 1e-5f);
        }
        __syncthreads();

        // ---- normalize + store: 4x4 shfl transpose -> float4 stores.
        // gm/bt as float4 at the lane's post-transpose 4-col group.
        float4 g4[3], b4[3];
#pragma unroll
        for (int ct = 0; ct < 3; ++ct) {
            const int colq = wv * 96 + ct * 32 + (lm & ~3);
            g4[ct] = *reinterpret_cast<const float4*>(&gm[colq]);
            b4[ct] = *reinterpret_cast<const float4*>(&bt[colq]);
        }
#pragma unroll
        for (int rt = 0; rt < 2; ++rt) {
#pragma unroll
            for (int m = 0; m < 4; ++m) {
                const int row = rt * 32 + 8 * m + 4 * half + (lm & 3);
                const float mu = muA[row], rs = rsA[row];
#pragma unroll
                for (int ct = 0; ct < 3; ++ct) {
                    // quad values: M[i][j], i = lm&3 (lane pos), j = reg
                    const float v0 = acc[rt][ct][4 * m + 0];
                    const float v1 = acc[rt][ct][4 * m + 1];
                    const float v2 = acc[rt][ct][4 * m + 2];
                    const float v3 = acc[rt][ct][4 * m + 3];
                    // stage 1 (xor 1): B[j] = ((i^j)&1) ? shfl1(M[j^1]) : M[j]
                    const float t0 = __shfl_xor(v1, 1);
                    const float t1 = __shfl_xor(v0, 1);
                    const float t2 = __shfl_xor(v3, 1);
                    const float t3 = __shfl_xor(v2, 1);
                    const float b0 = ib0 ? t0 : v0;
                    const float b1 = ib0 ? v1 : t1;
                    const float b2 = ib0 ? t2 : v2;
                    const float b3 = ib0 ? v3 : t3;
                    // stage 2 (xor 2): C[j] = ((i^j)&2) ? shfl2(B[j^2]) : B[j]
                    const float u0 = __shfl_xor(b2, 2);
                    const float u1 = __shfl_xor(b3, 2);
                    const float u2 = __shfl_xor(b0, 2);
                    const float u3 = __shfl_xor(b1, 2);
                    const float c0 = ib1 ? u0 : b0;
                    const float c1 = ib1 ? u1 : b1;
                    const float c2 = ib1 ? b2 : u2;
                    const float c3 = ib1 ? b3 : u3;
                    // lane (quad q, pos i) now holds row `row`, cols colq..+3
                    float4 o;
                    o.x = (c0 - mu) * rs * g4[ct].x + b4[ct].x;
                    o.y = (c1 - mu) * rs * g4[ct].y + b4[ct].y;
                    o.z = (c2 - mu) * rs * g4[ct].z + b4[ct].z;
                    o.w = (c3 - mu) * rs * g4[ct].w + b4[ct].w;
                    *reinterpret_cast<float4*>(
                        &out[(size_t)(r0 + row) * DOUT + wv * 96 + ct * 32 + (lm & ~3)]) = o;
                }
            }
        }
        // no barrier needed before next pass: xh[0] (wavL) is not read by
        // any wave after the post-redS barrier; pass-2 staging targets it.
    }
}

// ---------------------------------------------------------------- launcher
extern "C" void kernel_launch(void* const* d_in, const int* in_sizes, int n_in,
                              void* d_out, int out_size, void* d_ws, size_t ws_size,
                              hipStream_t stream)
{
    const float* x  = (const float*)d_in[0];
    const float* W  = (const float*)d_in[1];
    const float* b  = (const float*)d_in[2];
    const float* Wp = (const float*)d_in[3];
    const float* bp = (const float*)d_in[4];
    const float* Wc = (const float*)d_in[5];
    const float* bc = (const float*)d_in[6];
    const float* sc = (const float*)d_in[7];
    const float* tr = (const float*)d_in[8];
    const float* gm = (const float*)d_in[9];
    const float* bt = (const float*)d_in[10];
    float* out = (float*)d_out;
    short* ws  = (short*)d_ws;   // ~1.45 MB packed weights

    void* args[] = {
        (void*)&x, (void*)&W, (void*)&Wp, (void*)&Wc, (void*)&ws,
        (void*)&bp, (void*)&sc, (void*)&tr, (void*)&b, (void*)&bc,
        (void*)&gm, (void*)&bt, (void*)&out
    };
    hipLaunchCooperativeKernel((void*)fused_kernel, dim3(256), dim3(512),
                               args, 0, stream);
}

// Round 8
// 285.681 us; speedup vs baseline: 1.6407x; 1.6407x over previous
//
#include <hip/hip_runtime.h>
#include <math.h>

// WaveletKANClassifier, MI355X gfx950. fp32 I/O, bf16 MFMA compute.
//
// Round-12: fused is FILL-BYTE bound (confirmed model: x96+W590+Wp196+
// Wc37+out96 = 1015 MB at ~12.4 B/cyc/CU fill = 127us ~= measured 133;
// R3 1670MB->153, R7 +230MB spill traffic->312 all fit). Register file
// caps rows/block at 64 (acc=rows*cols/64 regs), so W's 590 MB is fixed.
// The removable term: Wp was read 2x (wave pairs loaded identical tiles).
// This round: back to the proven R6 two-dispatch kernel, with the wi path
// on TWO waves only (wv 0,1), each owning one wct col-tile and BOTH
// row-tiles (wacc[2], 6 MFMA/ks). Same FLOPs, half the Wp fill (-98 MB).
// R7's shfl-transpose epilogue is dropped (register-pressure cliff ->
// scratch spills -> +230 MB traffic); scalar stores are fill-equivalent.

#define B_SZ  32768
#define DIN   768
#define DOUT  768
#define NWAV  48

// d_ws fragment-major layout (units: shorts). Fragment tile = 64 lanes x 8
// bf16 = 512 shorts; lane L holds M[c0+(L&31)][k0 + (L>>5)*8 + j].
#define WF_OFF   0        // W:  24 cb x 48 kb tiles = 589824
#define WPH_OFF  589824   // Wp hi: 2 ct x 48 kb = 49152
#define WPL_OFF  638976   // Wp lo: 49152
#define WCF_OFF  688128   // Wc: 24 cb x 3 kb = 36864

typedef short bf16x8 __attribute__((ext_vector_type(8)));
typedef float f32x16 __attribute__((ext_vector_type(16)));

__device__ __forceinline__ float bf2f(short u) {
    union { unsigned int i; float f; } v;
    v.i = ((unsigned int)(unsigned short)u) << 16;
    return v.f;
}
__device__ __forceinline__ short f2bf(float f) {
    union { float f; unsigned int i; } v; v.f = f;
    unsigned int r = v.i + 0x7FFFu + ((v.i >> 16) & 1u);  // RNE
    return (short)(r >> 16);
}

// ---------------------------------------------------------------- K0: pack
__global__ __launch_bounds__(256) void pack_kernel(
    const float* __restrict__ W, const float* __restrict__ Wp,
    const float* __restrict__ Wc, short* __restrict__ ws)
{
    const int gw = (blockIdx.x * 256 + threadIdx.x) >> 6;
    const int L  = threadIdx.x & 63;
    const int lm = L & 31, half = L >> 5;

    if (gw < 1152) {                       // W [768 x 768]
        const int cb = gw / 48, kb = gw % 48;
        const int row = cb * 32 + lm;
        const int k = kb * 16 + half * 8;
        bf16x8 o;
#pragma unroll
        for (int j = 0; j < 8; j++) o[j] = f2bf(W[(size_t)row * DIN + k + j]);
        *reinterpret_cast<bf16x8*>(&ws[WF_OFF + (size_t)gw * 512 + L * 8]) = o;
    } else if (gw < 1248) {                // Wp [48 x 768], hi/lo, pad rows->64
        const int t = gw - 1152;
        const int ct = t / 48, kb = t % 48;
        const int j = ct * 32 + lm;
        const int k = kb * 16 + half * 8;
        bf16x8 h, l;
#pragma unroll
        for (int jj = 0; jj < 8; jj++) {
            float v = (j < NWAV) ? Wp[(size_t)j * DIN + k + jj] : 0.f;
            const short hh = f2bf(v);
            h[jj] = hh;
            l[jj] = f2bf(v - bf2f(hh));
        }
        *reinterpret_cast<bf16x8*>(&ws[WPH_OFF + (size_t)t * 512 + L * 8]) = h;
        *reinterpret_cast<bf16x8*>(&ws[WPL_OFF + (size_t)t * 512 + L * 8]) = l;
    } else if (gw < 1320) {                // Wc [768 x 48]
        const int t = gw - 1248;
        const int cb = t / 3, kb = t % 3;
        const int row = cb * 32 + lm;
        const int k = kb * 16 + half * 8;
        bf16x8 o;
#pragma unroll
        for (int jj = 0; jj < 8; jj++) o[jj] = f2bf(Wc[(size_t)row * NWAV + k + jj]);
        *reinterpret_cast<bf16x8*>(&ws[WCF_OFF + (size_t)t * 512 + L * 8]) = o;
    }
}

// ---------------------------------------------------------------- K1: fused
// 64 rows x 768 cols per block, 8 waves x [64r x 96c], 512 blocks.
// Waves 0,1 additionally compute wi = x@Wp^T: wave wv owns wi cols
// [wv*32, wv*32+32) for BOTH 32-row tiles (wacc[2]) -> Wp tiles read once
// per block (no duplication).
__global__ __launch_bounds__(512, 2) void fused_kernel(
    const float* __restrict__ x, const short* __restrict__ ws,
    const float* __restrict__ Wp,
    const float* __restrict__ bp, const float* __restrict__ sc,
    const float* __restrict__ tr,
    const float* __restrict__ bb, const float* __restrict__ bc,
    const float* __restrict__ gm, const float* __restrict__ bt,
    float* __restrict__ out)
{
    // x tiles: 64 rows x 64 k bf16, row stride 72 shorts (9x16B granules,
    // coprime 8 -> near-conflict-free b128 frag reads). Double-buffered.
    __shared__ __align__(16) short xh[2][64 * 72];
    __shared__ __align__(16) short xl[2][64 * 72];
    __shared__ float redS[64 * 8], redQ[64 * 8];
    __shared__ float muA[64], rsA[64];
    __shared__ unsigned flags[64];      // bit j: (row, haar j) boundary band
    __shared__ double dred[8];

    const short* WF  = ws + WF_OFF;
    const short* WPH = ws + WPH_OFF;
    const short* WPL = ws + WPL_OFF;
    const short* WCF = ws + WCF_OFF;

    const int tid = threadIdx.x;
    const int r0  = blockIdx.x * 64;
    const int L   = tid & 63;
    const int wv  = __builtin_amdgcn_readfirstlane(tid >> 6);  // wave-uniform
    const int lm  = L & 31, half = L >> 5;
    const int L8  = L * 8;
    const bool wi = (wv < 2);      // waves 0,1: wi path, one wct each
    const int wv3 = wv * 3;
    const int wct48 = wv * 48;     // wi wave's Wp tile row (wct = wv)

    if (tid < 64) flags[tid] = 0u;

    f32x16 acc[2][3];              // [rt (row 32-block)][ct (col 32-block)]
#pragma unroll
    for (int rt = 0; rt < 2; rt++)
#pragma unroll
        for (int ct = 0; ct < 3; ct++)
#pragma unroll
            for (int g = 0; g < 16; g++) acc[rt][ct][g] = 0.f;
    f32x16 wacc[2];                // wi acc, both row-tiles (waves 0,1)
#pragma unroll
    for (int rt = 0; rt < 2; rt++)
#pragma unroll
        for (int g = 0; g < 16; g++) wacc[rt][g] = 0.f;

    // staging role: thread -> (row, 8-k chunk); 8 threads per row
    const int srow = tid >> 3;
    const int sk   = (tid & 7) * 8;

    // ---- prologue: stage x chunk 0 into buf 0
    {
        const float4* xp = reinterpret_cast<const float4*>(&x[(size_t)(r0 + srow) * DIN + sk]);
        const float4 v0 = xp[0], v1 = xp[1];
        const float f[8] = {v0.x, v0.y, v0.z, v0.w, v1.x, v1.y, v1.z, v1.w};
        bf16x8 hh, ll;
#pragma unroll
        for (int i = 0; i < 8; i++) {
            const short h = f2bf(f[i]);
            hh[i] = h;
            ll[i] = f2bf(f[i] - bf2f(h));
        }
        *reinterpret_cast<bf16x8*>(&xh[0][srow * 72 + sk]) = hh;
        *reinterpret_cast<bf16x8*>(&xl[0][srow * 72 + sk]) = ll;
    }
    __syncthreads();

    // ---- K loop: 12 chunks of 64
    for (int k0i = 0; k0i < 12; ++k0i) {
        const int cur = k0i & 1;
        const int kb0 = k0i * 4;

        // (1) issue ALL B-fragment loads of this chunk, back-to-back
        bf16x8 bfr[4][3];
#pragma unroll
        for (int ks = 0; ks < 4; ++ks)
#pragma unroll
            for (int ct = 0; ct < 3; ++ct)
                bfr[ks][ct] = *reinterpret_cast<const bf16x8*>(
                    &WF[((size_t)((wv3 + ct) * 48 + kb0 + ks)) * 512 + L8]);
        bf16x8 bwh[4], bwl[4];
        if (wi) {
#pragma unroll
            for (int ks = 0; ks < 4; ++ks) {
                bwh[ks] = *reinterpret_cast<const bf16x8*>(
                    &WPH[((size_t)(wct48 + kb0 + ks)) * 512 + L8]);
                bwl[ks] = *reinterpret_cast<const bf16x8*>(
                    &WPL[((size_t)(wct48 + kb0 + ks)) * 512 + L8]);
            }
        }

        // (2) x prefetch (consumed after the MFMA cluster)
        float4 v0, v1;
        if (k0i < 11) {
            const float4* xp = reinterpret_cast<const float4*>(
                &x[(size_t)(r0 + srow) * DIN + (k0i + 1) * 64 + sk]);
            v0 = xp[0]; v1 = xp[1];
        }

        __builtin_amdgcn_sched_barrier(0);

        // (4) MFMA cluster: 2 rt x 3 ct x 4 ks (+6 wi per ks on waves 0,1)
#pragma unroll
        for (int ks = 0; ks < 4; ++ks) {
            const bf16x8 a0 = *reinterpret_cast<bf16x8*>(
                &xh[cur][lm * 72 + ks * 16 + half * 8]);
            const bf16x8 a1 = *reinterpret_cast<bf16x8*>(
                &xh[cur][(32 + lm) * 72 + ks * 16 + half * 8]);
#pragma unroll
            for (int ct = 0; ct < 3; ++ct) {
                acc[0][ct] = __builtin_amdgcn_mfma_f32_32x32x16_bf16(a0, bfr[ks][ct], acc[0][ct], 0, 0, 0);
                acc[1][ct] = __builtin_amdgcn_mfma_f32_32x32x16_bf16(a1, bfr[ks][ct], acc[1][ct], 0, 0, 0);
            }
            if (wi) {
                const bf16x8 al0 = *reinterpret_cast<bf16x8*>(
                    &xl[cur][lm * 72 + ks * 16 + half * 8]);
                const bf16x8 al1 = *reinterpret_cast<bf16x8*>(
                    &xl[cur][(32 + lm) * 72 + ks * 16 + half * 8]);
                wacc[0] = __builtin_amdgcn_mfma_f32_32x32x16_bf16(a0,  bwl[ks], wacc[0], 0, 0, 0);
                wacc[0] = __builtin_amdgcn_mfma_f32_32x32x16_bf16(al0, bwh[ks], wacc[0], 0, 0, 0);
                wacc[0] = __builtin_amdgcn_mfma_f32_32x32x16_bf16(a0,  bwh[ks], wacc[0], 0, 0, 0);
                wacc[1] = __builtin_amdgcn_mfma_f32_32x32x16_bf16(a1,  bwl[ks], wacc[1], 0, 0, 0);
                wacc[1] = __builtin_amdgcn_mfma_f32_32x32x16_bf16(al1, bwh[ks], wacc[1], 0, 0, 0);
                wacc[1] = __builtin_amdgcn_mfma_f32_32x32x16_bf16(a1,  bwh[ks], wacc[1], 0, 0, 0);
            }
        }

        // (5) stage next x chunk into 1-cur
        if (k0i < 11) {
            const float f[8] = {v0.x, v0.y, v0.z, v0.w, v1.x, v1.y, v1.z, v1.w};
            bf16x8 hh, ll;
#pragma unroll
            for (int i = 0; i < 8; i++) {
                const short h = f2bf(f[i]);
                hh[i] = h;
                ll[i] = f2bf(f[i] - bf2f(h));
            }
            *reinterpret_cast<bf16x8*>(&xh[1 - cur][srow * 72 + sk]) = hh;
            *reinterpret_cast<bf16x8*>(&xl[1 - cur][srow * 72 + sk]) = ll;
        }
        __syncthreads();
    }

    // ---- wavelet activation + GELU -> wav tile in LDS (reuse xh[0])
    short* wavL = &xh[0][0];
    if (wi) {
        const int j = wv * 32 + lm;
        if (j < NWAV) {
            const float bpv = bp[j], scv = sc[j], trv = tr[j];
#pragma unroll
            for (int rt = 0; rt < 2; ++rt) {
#pragma unroll
                for (int g = 0; g < 16; ++g) {
                    const int rowl = rt * 32 + (g & 3) + 8 * (g >> 2) + 4 * half;  // C/D map
                    const float wiv = wacc[rt][g] + bpv;
                    const float s = (wiv - trv) / scv;
                    float w;
                    if (j < 16) {
                        // haar: flag boundary band for the in-block recheck
                        const float dmin = fminf(fabsf(s), fminf(fabsf(s - 0.5f), fabsf(s - 1.0f)));
                        if (dmin < 2e-4f) atomicOr(&flags[rowl], 1u << j);
                        w = (s >= 0.f && s < 0.5f) ? 1.f : ((s >= 0.5f && s < 1.f) ? -1.f : 0.f);
                    } else if (j < 32) {
                        w = (1.f - s * s) * expf(-0.5f * s * s);
                    } else {
                        w = cosf(5.f * s) * expf(-0.5f * s * s);
                    }
                    const float gel = 0.5f * w * (1.f + erff(w * 0.70710678118654752f));
                    wavL[rowl * 72 + j] = f2bf(gel);
                }
            }
        }
    }
    __syncthreads();

    // ---- block-parallel fp64 recheck of flagged (row, j) haar entries.
    // Rare; uniform control flow: all 512 threads walk the same LDS flag
    // words; each recheck is a cooperative 768-term fp64 dot, patching
    // wavL before the Wc MFMA.
#pragma unroll 1
    for (int fr = 0; fr < 64; ++fr) {
        unsigned m = flags[fr];
        while (m) {
            const int j = __ffs(m) - 1;
            m &= m - 1;
            const float* xr = &x[(size_t)(r0 + fr) * DIN];
            const float* wr = &Wp[(size_t)j * DIN];
            double a = (double)xr[tid] * (double)wr[tid];
            if (tid < DIN - 512)
                a += (double)xr[tid + 512] * (double)wr[tid + 512];
            a += __shfl_xor(a, 1);  a += __shfl_xor(a, 2);
            a += __shfl_xor(a, 4);  a += __shfl_xor(a, 8);
            a += __shfl_xor(a, 16); a += __shfl_xor(a, 32);
            if (L == 0) dred[wv] = a;
            __syncthreads();
            if (tid == 0) {
                double wid = (double)bp[j];
#pragma unroll
                for (int i = 0; i < 8; i++) wid += dred[i];
                const double sd = (wid - (double)tr[j]) / (double)sc[j];
                const double w = (sd >= 0.0 && sd < 0.5) ? 1.0
                               : ((sd >= 0.5 && sd < 1.0) ? -1.0 : 0.0);
                const double gel = 0.5 * w * (1.0 + erf(w * 0.70710678118654752));
                wavL[fr * 72 + j] = f2bf((float)gel);
            }
            __syncthreads();
        }
    }

    // ---- h += wav @ Wc^T  (K=48 -> 3 ksteps)
#pragma unroll
    for (int ks = 0; ks < 3; ++ks) {
        const bf16x8 a0 = *reinterpret_cast<bf16x8*>(&wavL[lm * 72 + ks * 16 + half * 8]);
        const bf16x8 a1 = *reinterpret_cast<bf16x8*>(&wavL[(32 + lm) * 72 + ks * 16 + half * 8]);
#pragma unroll
        for (int ct = 0; ct < 3; ++ct) {
            const bf16x8 b = *reinterpret_cast<const bf16x8*>(
                &WCF[((size_t)((wv3 + ct) * 3 + ks)) * 512 + L8]);
            acc[0][ct] = __builtin_amdgcn_mfma_f32_32x32x16_bf16(a0, b, acc[0][ct], 0, 0, 0);
            acc[1][ct] = __builtin_amdgcn_mfma_f32_32x32x16_bf16(a1, b, acc[1][ct], 0, 0, 0);
        }
    }

    // ---- bias + LN reduction
    float bias[3], gmv[3], btv[3];
#pragma unroll
    for (int ct = 0; ct < 3; ++ct) {
        const int col = wv * 96 + ct * 32 + lm;
        bias[ct] = bb[col] + bc[col];
        gmv[ct] = gm[col];
        btv[ct] = bt[col];
    }
#pragma unroll
    for (int rt = 0; rt < 2; ++rt) {
#pragma unroll
        for (int g = 0; g < 16; ++g) {
            const float v0 = acc[rt][0][g] + bias[0];
            const float v1 = acc[rt][1][g] + bias[1];
            const float v2 = acc[rt][2][g] + bias[2];
            acc[rt][0][g] = v0; acc[rt][1][g] = v1; acc[rt][2][g] = v2;
            float s1 = v0 + v1 + v2;
            float s2 = v0 * v0 + v1 * v1 + v2 * v2;
            // reduce across the 32 lanes of this half (same output row)
            s1 += __shfl_xor(s1, 1);  s2 += __shfl_xor(s2, 1);
            s1 += __shfl_xor(s1, 2);  s2 += __shfl_xor(s2, 2);
            s1 += __shfl_xor(s1, 4);  s2 += __shfl_xor(s2, 4);
            s1 += __shfl_xor(s1, 8);  s2 += __shfl_xor(s2, 8);
            s1 += __shfl_xor(s1, 16); s2 += __shfl_xor(s2, 16);
            if (lm == 0) {
                const int rowl = rt * 32 + (g & 3) + 8 * (g >> 2) + 4 * half;
                redS[rowl * 8 + wv] = s1;
                redQ[rowl * 8 + wv] = s2;
            }
        }
    }
    __syncthreads();
    if (tid < 64) {
        float S = 0.f, Q = 0.f;
#pragma unroll
        for (int i = 0; i < 8; i++) { S += redS[tid * 8 + i]; Q += redQ[tid * 8 + i]; }
        const float mu = S * (1.f / 768.f);
        const float var = Q * (1.f / 768.f) - mu * mu;
        muA[tid] = mu;
        rsA[tid] = rsqrtf(var + 1e-5f);
    }
    __syncthreads();

    // ---- normalize + store (f32)
#pragma unroll
    for (int rt = 0; rt < 2; ++rt) {
#pragma unroll
        for (int g = 0; g < 16; ++g) {
            const int rowl = rt * 32 + (g & 3) + 8 * (g >> 2) + 4 * half;
            const float mu = muA[rowl], rs = rsA[rowl];
            float* orow = &out[(size_t)(r0 + rowl) * DOUT + wv * 96 + lm];
#pragma unroll
            for (int ct = 0; ct < 3; ++ct) {
                orow[ct * 32] = (acc[rt][ct][g] - mu) * rs * gmv[ct] + btv[ct];
            }
        }
    }
}

// ---------------------------------------------------------------- launcher
extern "C" void kernel_launch(void* const* d_in, const int* in_sizes, int n_in,
                              void* d_out, int out_size, void* d_ws, size_t ws_size,
                              hipStream_t stream)
{
    const float* x  = (const float*)d_in[0];
    const float* W  = (const float*)d_in[1];
    const float* b  = (const float*)d_in[2];
    const float* Wp = (const float*)d_in[3];
    const float* bp = (const float*)d_in[4];
    const float* Wc = (const float*)d_in[5];
    const float* bc = (const float*)d_in[6];
    const float* sc = (const float*)d_in[7];
    const float* tr = (const float*)d_in[8];
    const float* gm = (const float*)d_in[9];
    const float* bt = (const float*)d_in[10];
    float* out = (float*)d_out;
    short* ws  = (short*)d_ws;   // ~1.45 MB packed weights

    pack_kernel<<<dim3(330), dim3(256), 0, stream>>>(W, Wp, Wc, ws);
    fused_kernel<<<dim3(B_SZ / 64), dim3(512), 0, stream>>>(
        x, ws, Wp, bp, sc, tr, b, bc, gm, bt, out);
}

// Round 9
// 270.653 us; speedup vs baseline: 1.7318x; 1.0555x over previous
//
#include <hip/hip_runtime.h>
#include <math.h>

// WaveletKANClassifier, MI355X gfx950. fp32 I/O, bf16 MFMA compute.
//
// Round-13: exact R6 base (best: fused 132.6, total 264.9) + Wp dedup the
// BALANCED way. R8's lesson: in a barrier-per-chunk loop the slowest wave
// sets the pace — moving wi to 2 waves (6 MFMA/ks) regressed +17us even
// though it halved Wp fill. Here: wi stays 4 waves x 3 MFMA/ks (R6
// balance), and Wp tiles are deduped via LDS using the EXISTING chunk
// barrier for sync (no manual vmcnt): waves 0,1 load next chunk's Wp
// tiles (global, issued with the load batch -> latency hidden under the
// MFMA cluster) and ds_write them into a double-buffered 32KB LDS region
// during the staging phase; all 4 wi waves ds_read bh/bl from LDS.
// Writes hit buffer (1-cur), reads hit (cur) -> race-free via the
// chunk-end __syncthreads. Block Wp fill 32KB -> 16KB per chunk.

#define B_SZ  32768
#define DIN   768
#define DOUT  768
#define NWAV  48

// d_ws fragment-major layout (units: shorts). Fragment tile = 64 lanes x 8
// bf16 = 512 shorts; lane L holds M[c0+(L&31)][k0 + (L>>5)*8 + j].
#define WF_OFF   0        // W:  24 cb x 48 kb tiles = 589824
#define WPH_OFF  589824   // Wp hi: 2 ct x 48 kb = 49152
#define WPL_OFF  638976   // Wp lo: 49152
#define WCF_OFF  688128   // Wc: 24 cb x 3 kb = 36864

typedef short bf16x8 __attribute__((ext_vector_type(8)));
typedef float f32x16 __attribute__((ext_vector_type(16)));

__device__ __forceinline__ float bf2f(short u) {
    union { unsigned int i; float f; } v;
    v.i = ((unsigned int)(unsigned short)u) << 16;
    return v.f;
}
__device__ __forceinline__ short f2bf(float f) {
    union { float f; unsigned int i; } v; v.f = f;
    unsigned int r = v.i + 0x7FFFu + ((v.i >> 16) & 1u);  // RNE
    return (short)(r >> 16);
}

// ---------------------------------------------------------------- K0: pack
__global__ __launch_bounds__(256) void pack_kernel(
    const float* __restrict__ W, const float* __restrict__ Wp,
    const float* __restrict__ Wc, short* __restrict__ ws)
{
    const int gw = (blockIdx.x * 256 + threadIdx.x) >> 6;
    const int L  = threadIdx.x & 63;
    const int lm = L & 31, half = L >> 5;

    if (gw < 1152) {                       // W [768 x 768]
        const int cb = gw / 48, kb = gw % 48;
        const int row = cb * 32 + lm;
        const int k = kb * 16 + half * 8;
        bf16x8 o;
#pragma unroll
        for (int j = 0; j < 8; j++) o[j] = f2bf(W[(size_t)row * DIN + k + j]);
        *reinterpret_cast<bf16x8*>(&ws[WF_OFF + (size_t)gw * 512 + L * 8]) = o;
    } else if (gw < 1248) {                // Wp [48 x 768], hi/lo, pad rows->64
        const int t = gw - 1152;
        const int ct = t / 48, kb = t % 48;
        const int j = ct * 32 + lm;
        const int k = kb * 16 + half * 8;
        bf16x8 h, l;
#pragma unroll
        for (int jj = 0; jj < 8; jj++) {
            float v = (j < NWAV) ? Wp[(size_t)j * DIN + k + jj] : 0.f;
            const short hh = f2bf(v);
            h[jj] = hh;
            l[jj] = f2bf(v - bf2f(hh));
        }
        *reinterpret_cast<bf16x8*>(&ws[WPH_OFF + (size_t)t * 512 + L * 8]) = h;
        *reinterpret_cast<bf16x8*>(&ws[WPL_OFF + (size_t)t * 512 + L * 8]) = l;
    } else if (gw < 1320) {                // Wc [768 x 48]
        const int t = gw - 1248;
        const int cb = t / 3, kb = t % 3;
        const int row = cb * 32 + lm;
        const int k = kb * 16 + half * 8;
        bf16x8 o;
#pragma unroll
        for (int jj = 0; jj < 8; jj++) o[jj] = f2bf(Wc[(size_t)row * NWAV + k + jj]);
        *reinterpret_cast<bf16x8*>(&ws[WCF_OFF + (size_t)t * 512 + L * 8]) = o;
    }
}

// ---------------------------------------------------------------- K1: fused
// 64 rows x 768 cols per block, 8 waves x [64r x 96c], 512 blocks.
// wi = x@Wp^T on waves 0-3 (3 MFMA/ks each, R6 balance); Wp bh/bl
// fragments come from a double-buffered LDS stage written by waves 0,1.
__global__ __launch_bounds__(512, 2) void fused_kernel(
    const float* __restrict__ x, const short* __restrict__ ws,
    const float* __restrict__ Wp,
    const float* __restrict__ bp, const float* __restrict__ sc,
    const float* __restrict__ tr,
    const float* __restrict__ bb, const float* __restrict__ bc,
    const float* __restrict__ gm, const float* __restrict__ bt,
    float* __restrict__ out)
{
    // x tiles: 64 rows x 64 k bf16, row stride 72 shorts (9x16B granules,
    // coprime 8 -> near-conflict-free b128 frag reads). Double-buffered.
    __shared__ __align__(16) short xh[2][64 * 72];
    __shared__ __align__(16) short xl[2][64 * 72];
    // Wp fragment stage: [buf][wct][ks][hi/lo][512 shorts] = 32 KB
    __shared__ __align__(16) short wpb[2][2][4][2][512];
    __shared__ float redS[64 * 8], redQ[64 * 8];
    __shared__ float muA[64], rsA[64];
    __shared__ unsigned flags[64];      // bit j: (row, haar j) boundary band
    __shared__ double dred[8];

    const short* WF  = ws + WF_OFF;
    const short* WPH = ws + WPH_OFF;
    const short* WPL = ws + WPL_OFF;
    const short* WCF = ws + WCF_OFF;

    const int tid = threadIdx.x;
    const int r0  = blockIdx.x * 64;
    const int L   = tid & 63;
    const int wv  = __builtin_amdgcn_readfirstlane(tid >> 6);  // wave-uniform
    const int lm  = L & 31, half = L >> 5;
    const int L8  = L * 8;
    const bool wi = (wv < 4);      // waves 0-3 compute wi = x@Wp^T
    const bool st = (wv < 2);      // waves 0,1 stage Wp tiles into LDS
    const int wv3 = wv * 3;
    const int wrt = wv & 1, wct = wv >> 1;     // wi tile for wv<4

    if (tid < 64) flags[tid] = 0u;

    f32x16 acc[2][3];              // [rt (row 32-block)][ct (col 32-block)]
#pragma unroll
    for (int rt = 0; rt < 2; rt++)
#pragma unroll
        for (int ct = 0; ct < 3; ct++)
#pragma unroll
            for (int g = 0; g < 16; g++) acc[rt][ct][g] = 0.f;
    f32x16 wacc;                   // wi acc (waves 0-3)
#pragma unroll
    for (int g = 0; g < 16; g++) wacc[g] = 0.f;

    // staging role: thread -> (row, 8-k chunk); 8 threads per row
    const int srow = tid >> 3;
    const int sk   = (tid & 7) * 8;

    // ---- prologue: stage x chunk 0 into buf 0; waves 0,1 stage Wp chunk 0
    {
        const float4* xp = reinterpret_cast<const float4*>(&x[(size_t)(r0 + srow) * DIN + sk]);
        const float4 v0 = xp[0], v1 = xp[1];
        const float f[8] = {v0.x, v0.y, v0.z, v0.w, v1.x, v1.y, v1.z, v1.w};
        bf16x8 hh, ll;
#pragma unroll
        for (int i = 0; i < 8; i++) {
            const short h = f2bf(f[i]);
            hh[i] = h;
            ll[i] = f2bf(f[i] - bf2f(h));
        }
        *reinterpret_cast<bf16x8*>(&xh[0][srow * 72 + sk]) = hh;
        *reinterpret_cast<bf16x8*>(&xl[0][srow * 72 + sk]) = ll;
    }
    if (st) {
#pragma unroll
        for (int ks = 0; ks < 4; ++ks) {
            const bf16x8 h = *reinterpret_cast<const bf16x8*>(
                &WPH[((size_t)(wv * 48 + ks)) * 512 + L8]);
            const bf16x8 l = *reinterpret_cast<const bf16x8*>(
                &WPL[((size_t)(wv * 48 + ks)) * 512 + L8]);
            *reinterpret_cast<bf16x8*>(&wpb[0][wv][ks][0][L8]) = h;
            *reinterpret_cast<bf16x8*>(&wpb[0][wv][ks][1][L8]) = l;
        }
    }
    __syncthreads();

    // ---- K loop: 12 chunks of 64
    for (int k0i = 0; k0i < 12; ++k0i) {
        const int cur = k0i & 1;
        const int kb0 = k0i * 4;

        // (1) issue ALL W B-fragment loads of this chunk, back-to-back
        bf16x8 bfr[4][3];
#pragma unroll
        for (int ks = 0; ks < 4; ++ks)
#pragma unroll
            for (int ct = 0; ct < 3; ++ct)
                bfr[ks][ct] = *reinterpret_cast<const bf16x8*>(
                    &WF[((size_t)((wv3 + ct) * 48 + kb0 + ks)) * 512 + L8]);

        // (2) waves 0,1: issue next chunk's Wp tile loads (written to LDS
        //     in step 5, so HBM/L2 latency hides under the MFMA cluster)
        bf16x8 nph[4], npl[4];
        if (st && k0i < 11) {
            const int kb0n = kb0 + 4;
#pragma unroll
            for (int ks = 0; ks < 4; ++ks) {
                nph[ks] = *reinterpret_cast<const bf16x8*>(
                    &WPH[((size_t)(wv * 48 + kb0n + ks)) * 512 + L8]);
                npl[ks] = *reinterpret_cast<const bf16x8*>(
                    &WPL[((size_t)(wv * 48 + kb0n + ks)) * 512 + L8]);
            }
        }

        // (3) x prefetch (consumed after the MFMA cluster)
        float4 v0, v1;
        if (k0i < 11) {
            const float4* xp = reinterpret_cast<const float4*>(
                &x[(size_t)(r0 + srow) * DIN + (k0i + 1) * 64 + sk]);
            v0 = xp[0]; v1 = xp[1];
        }

        __builtin_amdgcn_sched_barrier(0);

        // (4) MFMA cluster: 2 rt x 3 ct x 4 ks (+3 wi per ks on waves 0-3;
        //     bh/bl come from the LDS stage, buffer `cur`)
#pragma unroll
        for (int ks = 0; ks < 4; ++ks) {
            const bf16x8 a0 = *reinterpret_cast<bf16x8*>(
                &xh[cur][lm * 72 + ks * 16 + half * 8]);
            const bf16x8 a1 = *reinterpret_cast<bf16x8*>(
                &xh[cur][(32 + lm) * 72 + ks * 16 + half * 8]);
#pragma unroll
            for (int ct = 0; ct < 3; ++ct) {
                acc[0][ct] = __builtin_amdgcn_mfma_f32_32x32x16_bf16(a0, bfr[ks][ct], acc[0][ct], 0, 0, 0);
                acc[1][ct] = __builtin_amdgcn_mfma_f32_32x32x16_bf16(a1, bfr[ks][ct], acc[1][ct], 0, 0, 0);
            }
            if (wi) {
                const bf16x8 ah = wrt ? a1 : a0;
                const bf16x8 al = *reinterpret_cast<bf16x8*>(
                    &xl[cur][(wrt * 32 + lm) * 72 + ks * 16 + half * 8]);
                const bf16x8 bh = *reinterpret_cast<const bf16x8*>(&wpb[cur][wct][ks][0][L8]);
                const bf16x8 bl = *reinterpret_cast<const bf16x8*>(&wpb[cur][wct][ks][1][L8]);
                wacc = __builtin_amdgcn_mfma_f32_32x32x16_bf16(ah, bl, wacc, 0, 0, 0);
                wacc = __builtin_amdgcn_mfma_f32_32x32x16_bf16(al, bh, wacc, 0, 0, 0);
                wacc = __builtin_amdgcn_mfma_f32_32x32x16_bf16(ah, bh, wacc, 0, 0, 0);
            }
        }

        // (5) stage next x chunk into 1-cur; waves 0,1 ds_write next Wp
        if (k0i < 11) {
            const float f[8] = {v0.x, v0.y, v0.z, v0.w, v1.x, v1.y, v1.z, v1.w};
            bf16x8 hh, ll;
#pragma unroll
            for (int i = 0; i < 8; i++) {
                const short h = f2bf(f[i]);
                hh[i] = h;
                ll[i] = f2bf(f[i] - bf2f(h));
            }
            *reinterpret_cast<bf16x8*>(&xh[1 - cur][srow * 72 + sk]) = hh;
            *reinterpret_cast<bf16x8*>(&xl[1 - cur][srow * 72 + sk]) = ll;
            if (st) {
#pragma unroll
                for (int ks = 0; ks < 4; ++ks) {
                    *reinterpret_cast<bf16x8*>(&wpb[1 - cur][wv][ks][0][L8]) = nph[ks];
                    *reinterpret_cast<bf16x8*>(&wpb[1 - cur][wv][ks][1][L8]) = npl[ks];
                }
            }
        }
        __syncthreads();
    }

    // ---- wavelet activation + GELU -> wav tile in LDS (reuse xh[0])
    short* wavL = &xh[0][0];
    if (wi) {
        const int j = wct * 32 + lm;
        if (j < NWAV) {
            const float bpv = bp[j], scv = sc[j], trv = tr[j];
#pragma unroll
            for (int g = 0; g < 16; ++g) {
                const int rowl = wrt * 32 + (g & 3) + 8 * (g >> 2) + 4 * half;  // C/D map
                const float wiv = wacc[g] + bpv;
                const float s = (wiv - trv) / scv;
                float w;
                if (j < 16) {
                    // haar: flag boundary band for the in-block recheck
                    const float dmin = fminf(fabsf(s), fminf(fabsf(s - 0.5f), fabsf(s - 1.0f)));
                    if (dmin < 2e-4f) atomicOr(&flags[rowl], 1u << j);
                    w = (s >= 0.f && s < 0.5f) ? 1.f : ((s >= 0.5f && s < 1.f) ? -1.f : 0.f);
                } else if (j < 32) {
                    w = (1.f - s * s) * expf(-0.5f * s * s);
                } else {
                    w = cosf(5.f * s) * expf(-0.5f * s * s);
                }
                const float gel = 0.5f * w * (1.f + erff(w * 0.70710678118654752f));
                wavL[rowl * 72 + j] = f2bf(gel);
            }
        }
    }
    __syncthreads();

    // ---- block-parallel fp64 recheck of flagged (row, j) haar entries.
#pragma unroll 1
    for (int fr = 0; fr < 64; ++fr) {
        unsigned m = flags[fr];
        while (m) {
            const int j = __ffs(m) - 1;
            m &= m - 1;
            const float* xr = &x[(size_t)(r0 + fr) * DIN];
            const float* wr = &Wp[(size_t)j * DIN];
            double a = (double)xr[tid] * (double)wr[tid];
            if (tid < DIN - 512)
                a += (double)xr[tid + 512] * (double)wr[tid + 512];
            a += __shfl_xor(a, 1);  a += __shfl_xor(a, 2);
            a += __shfl_xor(a, 4);  a += __shfl_xor(a, 8);
            a += __shfl_xor(a, 16); a += __shfl_xor(a, 32);
            if (L == 0) dred[wv] = a;
            __syncthreads();
            if (tid == 0) {
                double wid = (double)bp[j];
#pragma unroll
                for (int i = 0; i < 8; i++) wid += dred[i];
                const double sd = (wid - (double)tr[j]) / (double)sc[j];
                const double w = (sd >= 0.0 && sd < 0.5) ? 1.0
                               : ((sd >= 0.5 && sd < 1.0) ? -1.0 : 0.0);
                const double gel = 0.5 * w * (1.0 + erf(w * 0.70710678118654752));
                wavL[fr * 72 + j] = f2bf((float)gel);
            }
            __syncthreads();
        }
    }

    // ---- h += wav @ Wc^T  (K=48 -> 3 ksteps)
#pragma unroll
    for (int ks = 0; ks < 3; ++ks) {
        const bf16x8 a0 = *reinterpret_cast<bf16x8*>(&wavL[lm * 72 + ks * 16 + half * 8]);
        const bf16x8 a1 = *reinterpret_cast<bf16x8*>(&wavL[(32 + lm) * 72 + ks * 16 + half * 8]);
#pragma unroll
        for (int ct = 0; ct < 3; ++ct) {
            const bf16x8 b = *reinterpret_cast<const bf16x8*>(
                &WCF[((size_t)((wv3 + ct) * 3 + ks)) * 512 + L8]);
            acc[0][ct] = __builtin_amdgcn_mfma_f32_32x32x16_bf16(a0, b, acc[0][ct], 0, 0, 0);
            acc[1][ct] = __builtin_amdgcn_mfma_f32_32x32x16_bf16(a1, b, acc[1][ct], 0, 0, 0);
        }
    }

    // ---- bias + LN reduction
    float bias[3], gmv[3], btv[3];
#pragma unroll
    for (int ct = 0; ct < 3; ++ct) {
        const int col = wv * 96 + ct * 32 + lm;
        bias[ct] = bb[col] + bc[col];
        gmv[ct] = gm[col];
        btv[ct] = bt[col];
    }
#pragma unroll
    for (int rt = 0; rt < 2; ++rt) {
#pragma unroll
        for (int g = 0; g < 16; ++g) {
            const float v0 = acc[rt][0][g] + bias[0];
            const float v1 = acc[rt][1][g] + bias[1];
            const float v2 = acc[rt][2][g] + bias[2];
            acc[rt][0][g] = v0; acc[rt][1][g] = v1; acc[rt][2][g] = v2;
            float s1 = v0 + v1 + v2;
            float s2 = v0 * v0 + v1 * v1 + v2 * v2;
            // reduce across the 32 lanes of this half (same output row)
            s1 += __shfl_xor(s1, 1);  s2 += __shfl_xor(s2, 1);
            s1 += __shfl_xor(s1, 2);  s2 += __shfl_xor(s2, 2);
            s1 += __shfl_xor(s1, 4);  s2 += __shfl_xor(s2, 4);
            s1 += __shfl_xor(s1, 8);  s2 += __shfl_xor(s2, 8);
            s1 += __shfl_xor(s1, 16); s2 += __shfl_xor(s2, 16);
            if (lm == 0) {
                const int rowl = rt * 32 + (g & 3) + 8 * (g >> 2) + 4 * half;
                redS[rowl * 8 + wv] = s1;
                redQ[rowl * 8 + wv] = s2;
            }
        }
    }
    __syncthreads();
    if (tid < 64) {
        float S = 0.f, Q = 0.f;
#pragma unroll
        for (int i = 0; i < 8; i++) { S += redS[tid * 8 + i]; Q += redQ[tid * 8 + i]; }
        const float mu = S * (1.f / 768.f);
        const float var = Q * (1.f / 768.f) - mu * mu;
        muA[tid] = mu;
        rsA[tid] = rsqrtf(var + 1e-5f);
    }
    __syncthreads();

    // ---- normalize + store (f32)
#pragma unroll
    for (int rt = 0; rt < 2; ++rt) {
#pragma unroll
        for (int g = 0; g < 16; ++g) {
            const int rowl = rt * 32 + (g & 3) + 8 * (g >> 2) + 4 * half;
            const float mu = muA[rowl], rs = rsA[rowl];
            float* orow = &out[(size_t)(r0 + rowl) * DOUT + wv * 96 + lm];
#pragma unroll
            for (int ct = 0; ct < 3; ++ct) {
                orow[ct * 32] = (acc[rt][ct][g] - mu) * rs * gmv[ct] + btv[ct];
            }
        }
    }
}

// ---------------------------------------------------------------- launcher
extern "C" void kernel_launch(void* const* d_in, const int* in_sizes, int n_in,
                              void* d_out, int out_size, void* d_ws, size_t ws_size,
                              hipStream_t stream)
{
    const float* x  = (const float*)d_in[0];
    const float* W  = (const float*)d_in[1];
    const float* b  = (const float*)d_in[2];
    const float* Wp = (const float*)d_in[3];
    const float* bp = (const float*)d_in[4];
    const float* Wc = (const float*)d_in[5];
    const float* bc = (const float*)d_in[6];
    const float* sc = (const float*)d_in[7];
    const float* tr = (const float*)d_in[8];
    const float* gm = (const float*)d_in[9];
    const float* bt = (const float*)d_in[10];
    float* out = (float*)d_out;
    short* ws  = (short*)d_ws;   // ~1.45 MB packed weights

    pack_kernel<<<dim3(330), dim3(256), 0, stream>>>(W, Wp, Wc, ws);
    fused_kernel<<<dim3(B_SZ / 64), dim3(512), 0, stream>>>(
        x, ws, Wp, bp, sc, tr, b, bc, gm, bt, out);
}

// Round 10
// 265.923 us; speedup vs baseline: 1.7627x; 1.0178x over previous
//
#include <hip/hip_runtime.h>
#include <math.h>

// WaveletKANClassifier, MI355X gfx950. fp32 I/O, bf16 MFMA compute.
//
// Round-14: halve the K-loop barriers. Evidence: chunk period 13.3k cyc,
// busy only ~4.5k, INVARIANT across load-mechanism/occupancy/tile/traffic
// changes (R1-R9); traffic cuts (Wp dedup) changed neither FETCH nor time
// => not BW-bound; the never-varied element is the per-chunk __syncthreads
// (12 barriers -> scheduling windows too short to overlap chunk k+1 load
// issue under chunk k MFMA, plus 8-wave skew at every fence).
// This round: supersteps of 2 chunks, 4-deep x LDS rotation (78.6 KB,
// free at 1 block/CU), ONE barrier per superstep. Staging writes buffers
// (k+2)&3,(k+3)&3 - disjoint from the two consumed -> race-free via the
// superstep barrier alone. No sched_barrier (proven null): the compiler
// may now hoist chunk-B loads under chunk-A MFMAs. Wp loads as R6.

#define B_SZ  32768
#define DIN   768
#define DOUT  768
#define NWAV  48

// d_ws fragment-major layout (units: shorts). Fragment tile = 64 lanes x 8
// bf16 = 512 shorts; lane L holds M[c0+(L&31)][k0 + (L>>5)*8 + j].
#define WF_OFF   0        // W:  24 cb x 48 kb tiles = 589824
#define WPH_OFF  589824   // Wp hi: 2 ct x 48 kb = 49152
#define WPL_OFF  638976   // Wp lo: 49152
#define WCF_OFF  688128   // Wc: 24 cb x 3 kb = 36864

typedef short bf16x8 __attribute__((ext_vector_type(8)));
typedef float f32x16 __attribute__((ext_vector_type(16)));

__device__ __forceinline__ float bf2f(short u) {
    union { unsigned int i; float f; } v;
    v.i = ((unsigned int)(unsigned short)u) << 16;
    return v.f;
}
__device__ __forceinline__ short f2bf(float f) {
    union { float f; unsigned int i; } v; v.f = f;
    unsigned int r = v.i + 0x7FFFu + ((v.i >> 16) & 1u);  // RNE
    return (short)(r >> 16);
}

// ---------------------------------------------------------------- K0: pack
__global__ __launch_bounds__(256) void pack_kernel(
    const float* __restrict__ W, const float* __restrict__ Wp,
    const float* __restrict__ Wc, short* __restrict__ ws)
{
    const int gw = (blockIdx.x * 256 + threadIdx.x) >> 6;
    const int L  = threadIdx.x & 63;
    const int lm = L & 31, half = L >> 5;

    if (gw < 1152) {                       // W [768 x 768]
        const int cb = gw / 48, kb = gw % 48;
        const int row = cb * 32 + lm;
        const int k = kb * 16 + half * 8;
        bf16x8 o;
#pragma unroll
        for (int j = 0; j < 8; j++) o[j] = f2bf(W[(size_t)row * DIN + k + j]);
        *reinterpret_cast<bf16x8*>(&ws[WF_OFF + (size_t)gw * 512 + L * 8]) = o;
    } else if (gw < 1248) {                // Wp [48 x 768], hi/lo, pad rows->64
        const int t = gw - 1152;
        const int ct = t / 48, kb = t % 48;
        const int j = ct * 32 + lm;
        const int k = kb * 16 + half * 8;
        bf16x8 h, l;
#pragma unroll
        for (int jj = 0; jj < 8; jj++) {
            float v = (j < NWAV) ? Wp[(size_t)j * DIN + k + jj] : 0.f;
            const short hh = f2bf(v);
            h[jj] = hh;
            l[jj] = f2bf(v - bf2f(hh));
        }
        *reinterpret_cast<bf16x8*>(&ws[WPH_OFF + (size_t)t * 512 + L * 8]) = h;
        *reinterpret_cast<bf16x8*>(&ws[WPL_OFF + (size_t)t * 512 + L * 8]) = l;
    } else if (gw < 1320) {                // Wc [768 x 48]
        const int t = gw - 1248;
        const int cb = t / 3, kb = t % 3;
        const int row = cb * 32 + lm;
        const int k = kb * 16 + half * 8;
        bf16x8 o;
#pragma unroll
        for (int jj = 0; jj < 8; jj++) o[jj] = f2bf(Wc[(size_t)row * NWAV + k + jj]);
        *reinterpret_cast<bf16x8*>(&ws[WCF_OFF + (size_t)t * 512 + L * 8]) = o;
    }
}

// ---------------------------------------------------------------- K1: fused
// 64 rows x 768 cols per block, 8 waves x [64r x 96c], 512 blocks.
__global__ __launch_bounds__(512, 2) void fused_kernel(
    const float* __restrict__ x, const short* __restrict__ ws,
    const float* __restrict__ Wp,
    const float* __restrict__ bp, const float* __restrict__ sc,
    const float* __restrict__ tr,
    const float* __restrict__ bb, const float* __restrict__ bc,
    const float* __restrict__ gm, const float* __restrict__ bt,
    float* __restrict__ out)
{
    // x tiles: 64 rows x 64 k bf16, row stride 72 shorts. FOUR buffers
    // (rotation k&3), hi + lo. One barrier per 2 chunks.
    __shared__ __align__(16) short xh[4][64 * 72];
    __shared__ __align__(16) short xl[4][64 * 72];
    __shared__ float redS[64 * 8], redQ[64 * 8];
    __shared__ float muA[64], rsA[64];
    __shared__ unsigned flags[64];      // bit j: (row, haar j) boundary band
    __shared__ double dred[8];

    const short* WF  = ws + WF_OFF;
    const short* WPH = ws + WPH_OFF;
    const short* WPL = ws + WPL_OFF;
    const short* WCF = ws + WCF_OFF;

    const int tid = threadIdx.x;
    const int r0  = blockIdx.x * 64;
    const int L   = tid & 63;
    const int wv  = __builtin_amdgcn_readfirstlane(tid >> 6);  // wave-uniform
    const int lm  = L & 31, half = L >> 5;
    const int L8  = L * 8;
    const bool wi = (wv < 4);      // waves 0-3 also compute wi = x@Wp^T
    const int wv3 = wv * 3;
    const int wrt = wv & 1, wct = wv >> 1;     // wi tile for wv<4
    const int wct48 = wct * 48;

    if (tid < 64) flags[tid] = 0u;

    f32x16 acc[2][3];              // [rt (row 32-block)][ct (col 32-block)]
#pragma unroll
    for (int rt = 0; rt < 2; rt++)
#pragma unroll
        for (int ct = 0; ct < 3; ct++)
#pragma unroll
            for (int g = 0; g < 16; g++) acc[rt][ct][g] = 0.f;
    f32x16 wacc;                   // wi acc (waves 0-3)
#pragma unroll
    for (int g = 0; g < 16; g++) wacc[g] = 0.f;

    // staging role: thread -> (row, 8-k chunk); 8 threads per row
    const int srow = tid >> 3;
    const int sk   = (tid & 7) * 8;

    // ---- prologue: stage x chunks 0,1 into buffers 0,1
#pragma unroll
    for (int c = 0; c < 2; ++c) {
        const float4* xp = reinterpret_cast<const float4*>(
            &x[(size_t)(r0 + srow) * DIN + c * 64 + sk]);
        const float4 v0 = xp[0], v1 = xp[1];
        const float f[8] = {v0.x, v0.y, v0.z, v0.w, v1.x, v1.y, v1.z, v1.w};
        bf16x8 hh, ll;
#pragma unroll
        for (int i = 0; i < 8; i++) {
            const short h = f2bf(f[i]);
            hh[i] = h;
            ll[i] = f2bf(f[i] - bf2f(h));
        }
        *reinterpret_cast<bf16x8*>(&xh[c][srow * 72 + sk]) = hh;
        *reinterpret_cast<bf16x8*>(&xl[c][srow * 72 + sk]) = ll;
    }
    __syncthreads();

    // ---- K loop: 6 supersteps of 2 chunks
    for (int s = 0; s < 6; ++s) {
        const int kA = 2 * s, kB = 2 * s + 1;
        const int bA = kA & 3, bB = kB & 3;
        const int kbA = kA * 4, kbB = kB * 4;

        // ---- chunk A: weight loads
        bf16x8 bfrA[4][3];
#pragma unroll
        for (int ks = 0; ks < 4; ++ks)
#pragma unroll
            for (int ct = 0; ct < 3; ++ct)
                bfrA[ks][ct] = *reinterpret_cast<const bf16x8*>(
                    &WF[((size_t)((wv3 + ct) * 48 + kbA + ks)) * 512 + L8]);
        bf16x8 bwhA[4], bwlA[4];
        if (wi) {
#pragma unroll
            for (int ks = 0; ks < 4; ++ks) {
                bwhA[ks] = *reinterpret_cast<const bf16x8*>(
                    &WPH[((size_t)(wct48 + kbA + ks)) * 512 + L8]);
                bwlA[ks] = *reinterpret_cast<const bf16x8*>(
                    &WPL[((size_t)(wct48 + kbA + ks)) * 512 + L8]);
            }
        }
        // x prefetch for chunk kA+2
        float4 vA0, vA1;
        if (s < 5) {
            const float4* xp = reinterpret_cast<const float4*>(
                &x[(size_t)(r0 + srow) * DIN + (kA + 2) * 64 + sk]);
            vA0 = xp[0]; vA1 = xp[1];
        }

        // ---- chunk A: MFMA
#pragma unroll
        for (int ks = 0; ks < 4; ++ks) {
            const bf16x8 a0 = *reinterpret_cast<bf16x8*>(
                &xh[bA][lm * 72 + ks * 16 + half * 8]);
            const bf16x8 a1 = *reinterpret_cast<bf16x8*>(
                &xh[bA][(32 + lm) * 72 + ks * 16 + half * 8]);
#pragma unroll
            for (int ct = 0; ct < 3; ++ct) {
                acc[0][ct] = __builtin_amdgcn_mfma_f32_32x32x16_bf16(a0, bfrA[ks][ct], acc[0][ct], 0, 0, 0);
                acc[1][ct] = __builtin_amdgcn_mfma_f32_32x32x16_bf16(a1, bfrA[ks][ct], acc[1][ct], 0, 0, 0);
            }
            if (wi) {
                const bf16x8 ah = wrt ? a1 : a0;
                const bf16x8 al = *reinterpret_cast<bf16x8*>(
                    &xl[bA][(wrt * 32 + lm) * 72 + ks * 16 + half * 8]);
                wacc = __builtin_amdgcn_mfma_f32_32x32x16_bf16(ah, bwlA[ks], wacc, 0, 0, 0);
                wacc = __builtin_amdgcn_mfma_f32_32x32x16_bf16(al, bwhA[ks], wacc, 0, 0, 0);
                wacc = __builtin_amdgcn_mfma_f32_32x32x16_bf16(ah, bwhA[ks], wacc, 0, 0, 0);
            }
        }

        // ---- chunk B: weight loads (no fence above: may issue under MFMA A)
        bf16x8 bfrB[4][3];
#pragma unroll
        for (int ks = 0; ks < 4; ++ks)
#pragma unroll
            for (int ct = 0; ct < 3; ++ct)
                bfrB[ks][ct] = *reinterpret_cast<const bf16x8*>(
                    &WF[((size_t)((wv3 + ct) * 48 + kbB + ks)) * 512 + L8]);
        bf16x8 bwhB[4], bwlB[4];
        if (wi) {
#pragma unroll
            for (int ks = 0; ks < 4; ++ks) {
                bwhB[ks] = *reinterpret_cast<const bf16x8*>(
                    &WPH[((size_t)(wct48 + kbB + ks)) * 512 + L8]);
                bwlB[ks] = *reinterpret_cast<const bf16x8*>(
                    &WPL[((size_t)(wct48 + kbB + ks)) * 512 + L8]);
            }
        }
        // x prefetch for chunk kB+2
        float4 vB0, vB1;
        if (s < 5) {
            const float4* xp = reinterpret_cast<const float4*>(
                &x[(size_t)(r0 + srow) * DIN + (kB + 2) * 64 + sk]);
            vB0 = xp[0]; vB1 = xp[1];
        }

        // ---- chunk B: MFMA
#pragma unroll
        for (int ks = 0; ks < 4; ++ks) {
            const bf16x8 a0 = *reinterpret_cast<bf16x8*>(
                &xh[bB][lm * 72 + ks * 16 + half * 8]);
            const bf16x8 a1 = *reinterpret_cast<bf16x8*>(
                &xh[bB][(32 + lm) * 72 + ks * 16 + half * 8]);
#pragma unroll
            for (int ct = 0; ct < 3; ++ct) {
                acc[0][ct] = __builtin_amdgcn_mfma_f32_32x32x16_bf16(a0, bfrB[ks][ct], acc[0][ct], 0, 0, 0);
                acc[1][ct] = __builtin_amdgcn_mfma_f32_32x32x16_bf16(a1, bfrB[ks][ct], acc[1][ct], 0, 0, 0);
            }
            if (wi) {
                const bf16x8 ah = wrt ? a1 : a0;
                const bf16x8 al = *reinterpret_cast<bf16x8*>(
                    &xl[bB][(wrt * 32 + lm) * 72 + ks * 16 + half * 8]);
                wacc = __builtin_amdgcn_mfma_f32_32x32x16_bf16(ah, bwlB[ks], wacc, 0, 0, 0);
                wacc = __builtin_amdgcn_mfma_f32_32x32x16_bf16(al, bwhB[ks], wacc, 0, 0, 0);
                wacc = __builtin_amdgcn_mfma_f32_32x32x16_bf16(ah, bwhB[ks], wacc, 0, 0, 0);
            }
        }

        // ---- stage chunks kA+2, kB+2 into buffers (kA+2)&3, (kB+2)&3.
        // Disjoint from bA,bB; prior-superstep readers are past the last
        // barrier -> race-free.
        if (s < 5) {
            {
                const float f[8] = {vA0.x, vA0.y, vA0.z, vA0.w, vA1.x, vA1.y, vA1.z, vA1.w};
                bf16x8 hh, ll;
#pragma unroll
                for (int i = 0; i < 8; i++) {
                    const short h = f2bf(f[i]);
                    hh[i] = h;
                    ll[i] = f2bf(f[i] - bf2f(h));
                }
                const int bn = (kA + 2) & 3;
                *reinterpret_cast<bf16x8*>(&xh[bn][srow * 72 + sk]) = hh;
                *reinterpret_cast<bf16x8*>(&xl[bn][srow * 72 + sk]) = ll;
            }
            {
                const float f[8] = {vB0.x, vB0.y, vB0.z, vB0.w, vB1.x, vB1.y, vB1.z, vB1.w};
                bf16x8 hh, ll;
#pragma unroll
                for (int i = 0; i < 8; i++) {
                    const short h = f2bf(f[i]);
                    hh[i] = h;
                    ll[i] = f2bf(f[i] - bf2f(h));
                }
                const int bn = (kB + 2) & 3;
                *reinterpret_cast<bf16x8*>(&xh[bn][srow * 72 + sk]) = hh;
                *reinterpret_cast<bf16x8*>(&xl[bn][srow * 72 + sk]) = ll;
            }
        }
        __syncthreads();
    }

    // ---- wavelet activation + GELU -> wav tile in LDS (reuse xh[0])
    short* wavL = &xh[0][0];
    if (wi) {
        const int j = wct * 32 + lm;
        if (j < NWAV) {
            const float bpv = bp[j], scv = sc[j], trv = tr[j];
#pragma unroll
            for (int g = 0; g < 16; ++g) {
                const int rowl = wrt * 32 + (g & 3) + 8 * (g >> 2) + 4 * half;  // C/D map
                const float wiv = wacc[g] + bpv;
                const float s = (wiv - trv) / scv;
                float w;
                if (j < 16) {
                    // haar: flag boundary band for the in-block recheck
                    const float dmin = fminf(fabsf(s), fminf(fabsf(s - 0.5f), fabsf(s - 1.0f)));
                    if (dmin < 2e-4f) atomicOr(&flags[rowl], 1u << j);
                    w = (s >= 0.f && s < 0.5f) ? 1.f : ((s >= 0.5f && s < 1.f) ? -1.f : 0.f);
                } else if (j < 32) {
                    w = (1.f - s * s) * expf(-0.5f * s * s);
                } else {
                    w = cosf(5.f * s) * expf(-0.5f * s * s);
                }
                const float gel = 0.5f * w * (1.f + erff(w * 0.70710678118654752f));
                wavL[rowl * 72 + j] = f2bf(gel);
            }
        }
    }
    __syncthreads();

    // ---- block-parallel fp64 recheck of flagged (row, j) haar entries.
#pragma unroll 1
    for (int fr = 0; fr < 64; ++fr) {
        unsigned m = flags[fr];
        while (m) {
            const int j = __ffs(m) - 1;
            m &= m - 1;
            const float* xr = &x[(size_t)(r0 + fr) * DIN];
            const float* wr = &Wp[(size_t)j * DIN];
            double a = (double)xr[tid] * (double)wr[tid];
            if (tid < DIN - 512)
                a += (double)xr[tid + 512] * (double)wr[tid + 512];
            a += __shfl_xor(a, 1);  a += __shfl_xor(a, 2);
            a += __shfl_xor(a, 4);  a += __shfl_xor(a, 8);
            a += __shfl_xor(a, 16); a += __shfl_xor(a, 32);
            if (L == 0) dred[wv] = a;
            __syncthreads();
            if (tid == 0) {
                double wid = (double)bp[j];
#pragma unroll
                for (int i = 0; i < 8; i++) wid += dred[i];
                const double sd = (wid - (double)tr[j]) / (double)sc[j];
                const double w = (sd >= 0.0 && sd < 0.5) ? 1.0
                               : ((sd >= 0.5 && sd < 1.0) ? -1.0 : 0.0);
                const double gel = 0.5 * w * (1.0 + erf(w * 0.70710678118654752));
                wavL[fr * 72 + j] = f2bf((float)gel);
            }
            __syncthreads();
        }
    }

    // ---- h += wav @ Wc^T  (K=48 -> 3 ksteps)
#pragma unroll
    for (int ks = 0; ks < 3; ++ks) {
        const bf16x8 a0 = *reinterpret_cast<bf16x8*>(&wavL[lm * 72 + ks * 16 + half * 8]);
        const bf16x8 a1 = *reinterpret_cast<bf16x8*>(&wavL[(32 + lm) * 72 + ks * 16 + half * 8]);
#pragma unroll
        for (int ct = 0; ct < 3; ++ct) {
            const bf16x8 b = *reinterpret_cast<const bf16x8*>(
                &WCF[((size_t)((wv3 + ct) * 3 + ks)) * 512 + L8]);
            acc[0][ct] = __builtin_amdgcn_mfma_f32_32x32x16_bf16(a0, b, acc[0][ct], 0, 0, 0);
            acc[1][ct] = __builtin_amdgcn_mfma_f32_32x32x16_bf16(a1, b, acc[1][ct], 0, 0, 0);
        }
    }

    // ---- bias + LN reduction
    float bias[3], gmv[3], btv[3];
#pragma unroll
    for (int ct = 0; ct < 3; ++ct) {
        const int col = wv * 96 + ct * 32 + lm;
        bias[ct] = bb[col] + bc[col];
        gmv[ct] = gm[col];
        btv[ct] = bt[col];
    }
#pragma unroll
    for (int rt = 0; rt < 2; ++rt) {
#pragma unroll
        for (int g = 0; g < 16; ++g) {
            const float v0 = acc[rt][0][g] + bias[0];
            const float v1 = acc[rt][1][g] + bias[1];
            const float v2 = acc[rt][2][g] + bias[2];
            acc[rt][0][g] = v0; acc[rt][1][g] = v1; acc[rt][2][g] = v2;
            float s1 = v0 + v1 + v2;
            float s2 = v0 * v0 + v1 * v1 + v2 * v2;
            // reduce across the 32 lanes of this half (same output row)
            s1 += __shfl_xor(s1, 1);  s2 += __shfl_xor(s2, 1);
            s1 += __shfl_xor(s1, 2);  s2 += __shfl_xor(s2, 2);
            s1 += __shfl_xor(s1, 4);  s2 += __shfl_xor(s2, 4);
            s1 += __shfl_xor(s1, 8);  s2 += __shfl_xor(s2, 8);
            s1 += __shfl_xor(s1, 16); s2 += __shfl_xor(s2, 16);
            if (lm == 0) {
                const int rowl = rt * 32 + (g & 3) + 8 * (g >> 2) + 4 * half;
                redS[rowl * 8 + wv] = s1;
                redQ[rowl * 8 + wv] = s2;
            }
        }
    }
    __syncthreads();
    if (tid < 64) {
        float S = 0.f, Q = 0.f;
#pragma unroll
        for (int i = 0; i < 8; i++) { S += redS[tid * 8 + i]; Q += redQ[tid * 8 + i]; }
        const float mu = S * (1.f / 768.f);
        const float var = Q * (1.f / 768.f) - mu * mu;
        muA[tid] = mu;
        rsA[tid] = rsqrtf(var + 1e-5f);
    }
    __syncthreads();

    // ---- normalize + store (f32)
#pragma unroll
    for (int rt = 0; rt < 2; ++rt) {
#pragma unroll
        for (int g = 0; g < 16; ++g) {
            const int rowl = rt * 32 + (g & 3) + 8 * (g >> 2) + 4 * half;
            const float mu = muA[rowl], rs = rsA[rowl];
            float* orow = &out[(size_t)(r0 + rowl) * DOUT + wv * 96 + lm];
#pragma unroll
            for (int ct = 0; ct < 3; ++ct) {
                orow[ct * 32] = (acc[rt][ct][g] - mu) * rs * gmv[ct] + btv[ct];
            }
        }
    }
}

// ---------------------------------------------------------------- launcher
extern "C" void kernel_launch(void* const* d_in, const int* in_sizes, int n_in,
                              void* d_out, int out_size, void* d_ws, size_t ws_size,
                              hipStream_t stream)
{
    const float* x  = (const float*)d_in[0];
    const float* W  = (const float*)d_in[1];
    const float* b  = (const float*)d_in[2];
    const float* Wp = (const float*)d_in[3];
    const float* bp = (const float*)d_in[4];
    const float* Wc = (const float*)d_in[5];
    const float* bc = (const float*)d_in[6];
    const float* sc = (const float*)d_in[7];
    const float* tr = (const float*)d_in[8];
    const float* gm = (const float*)d_in[9];
    const float* bt = (const float*)d_in[10];
    float* out = (float*)d_out;
    short* ws  = (short*)d_ws;   // ~1.45 MB packed weights

    pack_kernel<<<dim3(330), dim3(256), 0, stream>>>(W, Wp, Wc, ws);
    fused_kernel<<<dim3(B_SZ / 64), dim3(512), 0, stream>>>(
        x, ws, Wp, bp, sc, tr, b, bc, gm, bt, out);
}